// Round 4
// baseline (5050.934 us; speedup 1.0000x reference)
//
#include <hip/hip_runtime.h>

#define NB 256
#define NO 32
#define NEE 32
#define NT 16
#define NPAIR 496
#define THREADS 512

typedef const float* fp;

struct Params {
  fp z;
  fp ee1w, ee1b, ee2w, ee2b, ee3w, ee3b;
  fp ne1w, ne1b, ne2w, ne2b, ne3w, ne3b, ne4w, ne4b;
  fp le1w, le1b, le2w, le2b, le3w, le3b;
  fp lt1w, lt1b, lt2w, lt2b, lt3w, lt3b, lt4w, lt4b, lt5w, lt5b;
  float* out;
  int tf;
};

__device__ __forceinline__ float frelu(float x) { return x > 0.f ? x : 0.f; }

// out = sum_{k<n} sX[k] * W[k*ldw]; sX is an LDS row (lane-uniform addresses ->
// broadcast reads). W pre-offset to this lane's column.
__device__ __forceinline__ float dotL(const float* sX, const float* W, int n, int ldw) {
  float a0 = 0.f, a1 = 0.f, a2 = 0.f, a3 = 0.f;
#pragma unroll
  for (int k = 0; k < n; k += 4) {
    float4 x = *(const float4*)(sX + k);
    a0 = fmaf(x.x, W[(k    ) * ldw], a0);
    a1 = fmaf(x.y, W[(k + 1) * ldw], a1);
    a2 = fmaf(x.z, W[(k + 2) * ldw], a2);
    a3 = fmaf(x.w, W[(k + 3) * ldw], a3);
  }
  return (a0 + a1) + (a2 + a3);
}

__global__ __launch_bounds__(THREADS, 1) void rld_kernel(Params P) {
  const int b = blockIdx.x;
  const int tid = (int)threadIdx.x;
  const int lane = tid & 63;
  const int wave = tid >> 6;
  const int cc = lane & 31;
  const int c16 = lane & 15;

  __shared__ float sU[NO * 64];
  __shared__ float sV[NO * 64];
  __shared__ float sAgg[NO * 64];
  __shared__ float sBig[NO * 256];   // A1: sSrc.  A3/B: sZC | sN | sM overlay.
  __shared__ float sH[8 * 64];
  __shared__ unsigned char sII[NPAIR];
  __shared__ unsigned char sJJ[NPAIR];
  float* sSrc = sBig;
  float* sZC = sBig;                 // [0, 2048)
  float* sN  = sBig + NO * 64;      // [2048, 4096)
  float* sM  = sBig + NO * 128;     // [4096, 6144)

  // ---- pair index tables (np.triu_indices(32,1) order) ----
  for (int p = tid; p < NPAIR; p += THREADS) {
    int i = 0, rem = p;
    while (rem >= 31 - i) { rem -= 31 - i; ++i; }
    sII[p] = (unsigned char)i;
    sJJ[p] = (unsigned char)(i + 1 + rem);
  }

  const float* zb = P.z + (size_t)b * NT * NO * NEE;
  float* sHw = sH + wave * 64;

  // ===== Phase A1: u = src@ee1[:512], v = src@ee1[512:], s1 = src@ne1[:512] =====
  float au[4] = {0, 0, 0, 0}, av[4] = {0, 0, 0, 0}, s1r[4] = {0, 0, 0, 0};
  for (int half = 0; half < 2; ++half) {
    __syncthreads();  // protects sSrc reuse (and publishes tables on first pass)
    for (int idx = tid; idx < NO * 256; idx += THREADS) {
      int i = idx >> 8, kk = idx & 255;
      int k = half * 256 + kk;
      int t = k >> 5, e = k & 31;
      float v = zb[(t * NO + i) * NEE + e];
      if (t > 0) v -= zb[((t - 1) * NO + i) * NEE + e];
      sSrc[i * 256 + kk] = v;
    }
    __syncthreads();
    const float* wA = P.ee1w + (half * 256) * 64 + lane;
    const float* wB = P.ee1w + (512 + half * 256) * 64 + lane;
    const float* wC = P.ne1w + (half * 256) * 64 + lane;
#pragma unroll 4
    for (int kk = 0; kk < 256; ++kk) {
      float wa = wA[kk * 64];
      float wb = wB[kk * 64];
      float wc = wC[kk * 64];
#pragma unroll
      for (int r = 0; r < 4; ++r) {
        float s = sSrc[(wave + 8 * r) * 256 + kk];  // uniform broadcast read
        au[r]  = fmaf(s, wa, au[r]);
        av[r]  = fmaf(s, wb, av[r]);
        s1r[r] = fmaf(s, wc, s1r[r]);
      }
    }
  }
  __syncthreads();  // all sSrc reads done before sU/sV/sZC writes (overlay safety)
#pragma unroll
  for (int r = 0; r < 4; ++r) {
    sU[(wave + 8 * r) * 64 + lane] = au[r];
    sV[(wave + 8 * r) * 64 + lane] = av[r];
  }
  for (int idx = tid; idx < NO * 64; idx += THREADS) sAgg[idx] = 0.f;
  __syncthreads();

  // ===== Phase A2: ee edge MLP over 496 pairs =====
  {
    float eb1 = P.ee1b[lane];
    float eb2 = P.ee2b[lane];
    float eb3 = P.ee3b[lane];
    for (int r = 0; r < 62; ++r) {
      int p = wave * 62 + r;
      int i = sII[p], j = sJJ[p];
      float h1 = frelu(sU[i * 64 + lane] + sV[j * 64 + lane] + eb1);
      sHw[lane] = h1;                                      // same-wave LDS, in-order pipe
      float h2 = frelu(eb2 + dotL(sHw, P.ee2w + lane, 64, 64));
      sHw[lane] = h2;
      float e3 = eb3 + dotL(sHw, P.ee3w + lane, 64, 64);
      atomicAdd(&sAgg[i * 64 + lane], e3);
      atomicAdd(&sAgg[j * 64 + lane], -e3);
    }
  }
  __syncthreads();

  // ===== Phase A3: ne node MLP -> z_cur rows in sZC =====
  {
    float nb1 = P.ne1b[lane];
    float nb2 = P.ne2b[lane];
    float nb3 = P.ne3b[cc];
    float nb4 = P.ne4b[cc];
#pragma unroll
    for (int r = 0; r < 4; ++r) {
      int i = wave + 8 * r;
      float n1 = frelu(s1r[r] + nb1 + dotL(sAgg + i * 64, P.ne1w + 512 * 64 + lane, 64, 64));
      sN[i * 64 + lane] = n1;
      float n2 = frelu(nb2 + dotL(sN + i * 64, P.ne2w + lane, 64, 64));
      sM[i * 64 + lane] = n2;
      float n3 = frelu(nb3 + dotL(sM + i * 64, P.ne3w + cc, 64, 32));
      sN[i * 64 + cc] = n3;                                // both halves write same value
      float n4 = nb4 + dotL(sN + i * 64, P.ne4w + cc, 32, 32);
      if (lane < 32) {
        sZC[i * 64 + lane] = zb[(15 * NO + i) * NEE + lane];  // z[:, -1]
        sZC[i * 64 + 32 + lane] = n4;                          // z_impl
      }
    }
  }

  // ---- latent-phase biases ----
  float gb1 = P.le1b[lane];
  float gb2 = P.le2b[lane];
  float gb3 = P.le3b[lane];
  float lb1 = P.lt1b[lane];
  float lb2 = P.lt2b[lane];
  float lb3 = P.lt3b[cc];
  float lb4 = P.lt4b[c16];
  float lb5 = P.lt5b[lane];
  float* outb = P.out + (size_t)b * P.tf * NO * NEE;

  // ===== Phase B: t_future latent steps (2 barriers per step) =====
  for (int t = 0; t < P.tf; ++t) {
    // u = zc@le1[:64], v = zc@le1[64:], zero agg (own rows only)
#pragma unroll
    for (int r = 0; r < 4; ++r) {
      int i = wave + 8 * r;
      sU[i * 64 + lane] = dotL(sZC + i * 64, P.le1w + lane, 64, 64);
      sV[i * 64 + lane] = dotL(sZC + i * 64, P.le1w + 64 * 64 + lane, 64, 64);
      sAgg[i * 64 + lane] = 0.f;
    }
    __syncthreads();
    // le edge MLP over pairs
    for (int r = 0; r < 62; ++r) {
      int p = wave * 62 + r;
      int i = sII[p], j = sJJ[p];
      float h1 = frelu(sU[i * 64 + lane] + sV[j * 64 + lane] + gb1);
      sHw[lane] = h1;
      float h2 = frelu(gb2 + dotL(sHw, P.le2w + lane, 64, 64));
      sHw[lane] = h2;
      float e3 = gb3 + dotL(sHw, P.le3w + lane, 64, 64);
      atomicAdd(&sAgg[i * 64 + lane], e3);
      atomicAdd(&sAgg[j * 64 + lane], -e3);
    }
    __syncthreads();
    // lt node MLP, state update, output (own rows only)
#pragma unroll
    for (int r = 0; r < 4; ++r) {
      int i = wave + 8 * r;
      float l1 = frelu(lb1 + dotL(sZC + i * 64, P.lt1w + lane, 64, 64)
                           + dotL(sAgg + i * 64, P.lt1w + 64 * 64 + lane, 64, 64));
      sN[i * 64 + lane] = l1;
      float l2 = frelu(lb2 + dotL(sN + i * 64, P.lt2w + lane, 64, 64));
      sM[i * 64 + lane] = l2;
      float l3 = frelu(lb3 + dotL(sM + i * 64, P.lt3w + cc, 64, 32));
      sN[i * 64 + cc] = l3;
      float l4 = frelu(lb4 + dotL(sN + i * 64, P.lt4w + c16, 32, 16));
      if (lane < 16) sM[i * 64 + lane] = l4;
      float dl = lb5 + dotL(sM + i * 64, P.lt5w + lane, 16, 64);
      float zn = sZC[i * 64 + lane] + dl;
      sZC[i * 64 + lane] = zn;
      if (lane < 32) outb[(t * NO + i) * NEE + lane] = zn;
    }
  }
}

extern "C" void kernel_launch(void* const* d_in, const int* in_sizes, int n_in,
                              void* d_out, int out_size, void* d_ws, size_t ws_size,
                              hipStream_t stream) {
  (void)in_sizes; (void)n_in; (void)d_ws; (void)ws_size;
  Params P;
  int q = 0;
  P.z    = (fp)d_in[q++];
  P.ee1w = (fp)d_in[q++]; P.ee1b = (fp)d_in[q++];
  P.ee2w = (fp)d_in[q++]; P.ee2b = (fp)d_in[q++];
  P.ee3w = (fp)d_in[q++]; P.ee3b = (fp)d_in[q++];
  P.ne1w = (fp)d_in[q++]; P.ne1b = (fp)d_in[q++];
  P.ne2w = (fp)d_in[q++]; P.ne2b = (fp)d_in[q++];
  P.ne3w = (fp)d_in[q++]; P.ne3b = (fp)d_in[q++];
  P.ne4w = (fp)d_in[q++]; P.ne4b = (fp)d_in[q++];
  P.le1w = (fp)d_in[q++]; P.le1b = (fp)d_in[q++];
  P.le2w = (fp)d_in[q++]; P.le2b = (fp)d_in[q++];
  P.le3w = (fp)d_in[q++]; P.le3b = (fp)d_in[q++];
  P.lt1w = (fp)d_in[q++]; P.lt1b = (fp)d_in[q++];
  P.lt2w = (fp)d_in[q++]; P.lt2b = (fp)d_in[q++];
  P.lt3w = (fp)d_in[q++]; P.lt3b = (fp)d_in[q++];
  P.lt4w = (fp)d_in[q++]; P.lt4b = (fp)d_in[q++];
  P.lt5w = (fp)d_in[q++]; P.lt5b = (fp)d_in[q++];
  P.out = (float*)d_out;
  P.tf = out_size / (NB * NO * NEE);
  if (P.tf < 1) P.tf = 1;
  hipLaunchKernelGGL(rld_kernel, dim3(NB), dim3(THREADS), 0, stream, P);
}

// Round 5
// 2730.025 us; speedup vs baseline: 1.8501x; 1.8501x over previous
//
#include <hip/hip_runtime.h>

#define NB 256
#define NO 32
#define NEE 32
#define NT 16
#define NPAIR 496
#define THREADS 512

typedef const float* fp;

struct Params {
  fp z;
  fp ee1w, ee1b, ee2w, ee2b, ee3w, ee3b;
  fp ne1w, ne1b, ne2w, ne2b, ne3w, ne3b, ne4w, ne4b;
  fp le1w, le1b, le2w, le2b, le3w, le3b;
  fp lt1w, lt1b, lt2w, lt2b, lt3w, lt3b, lt4w, lt4b, lt5w, lt5b;
  float* out;
  int tf;
};

__device__ __forceinline__ float frelu(float x) { return x > 0.f ? x : 0.f; }

// 4-row fused dense layer: o[r] += sum_k x_r[k] * W[k*ldw]  (W pre-offset to
// this lane's output column; x_r are LDS rows read as uniform float4 -> LDS
// broadcast; one weight load serves 4 rows).
template<int KC>
__device__ __forceinline__ void dense4(const float* x0, const float* x1,
                                       const float* x2, const float* x3,
                                       const float* W, int ldw, float o[4]) {
#pragma unroll
  for (int kc = 0; kc < KC; ++kc) {
    float w0 = W[(4 * kc + 0) * ldw];
    float w1 = W[(4 * kc + 1) * ldw];
    float w2 = W[(4 * kc + 2) * ldw];
    float w3 = W[(4 * kc + 3) * ldw];
    float4 a = *(const float4*)(x0 + 4 * kc);
    float4 b = *(const float4*)(x1 + 4 * kc);
    float4 c = *(const float4*)(x2 + 4 * kc);
    float4 d = *(const float4*)(x3 + 4 * kc);
    o[0] = fmaf(a.x, w0, o[0]); o[0] = fmaf(a.y, w1, o[0]); o[0] = fmaf(a.z, w2, o[0]); o[0] = fmaf(a.w, w3, o[0]);
    o[1] = fmaf(b.x, w0, o[1]); o[1] = fmaf(b.y, w1, o[1]); o[1] = fmaf(b.z, w2, o[1]); o[1] = fmaf(b.w, w3, o[1]);
    o[2] = fmaf(c.x, w0, o[2]); o[2] = fmaf(c.y, w1, o[2]); o[2] = fmaf(c.z, w2, o[2]); o[2] = fmaf(c.w, w3, o[2]);
    o[3] = fmaf(d.x, w0, o[3]); o[3] = fmaf(d.y, w1, o[3]); o[3] = fmaf(d.z, w2, o[3]); o[3] = fmaf(d.w, w3, o[3]);
  }
}

// 64-MAC dot with register-resident weight column; x streamed as uniform b128
// from an LDS row. Returns sum (acc pre-loaded with bias).
__device__ __forceinline__ float dotR(const float* sX, const float (&w)[64], float bias) {
  float a0 = bias, a1 = 0.f, a2 = 0.f, a3 = 0.f;
#pragma unroll
  for (int kc = 0; kc < 16; ++kc) {
    float4 x = *(const float4*)(sX + 4 * kc);
    a0 = fmaf(x.x, w[4 * kc + 0], a0);
    a1 = fmaf(x.y, w[4 * kc + 1], a1);
    a2 = fmaf(x.z, w[4 * kc + 2], a2);
    a3 = fmaf(x.w, w[4 * kc + 3], a3);
  }
  return (a0 + a1) + (a2 + a3);
}

// Edge MLP over this wave's 62 pairs, 2 pairs in flight for ILP.
__device__ __forceinline__ void pair_block(const unsigned char* sII, const unsigned char* sJJ,
                                           const float* sU, const float* sV, float* sAgg,
                                           float* sH0, float* sH1, int wave, int lane,
                                           const float (&w2)[64], const float (&w3)[64],
                                           float b1, float b2, float b3) {
  const int base = wave * 62;
  for (int r = 0; r < 31; ++r) {
    int p0 = base + r, p1 = base + 31 + r;
    int i0 = sII[p0], j0 = sJJ[p0];
    int i1 = sII[p1], j1 = sJJ[p1];
    float h1a = frelu(sU[i0 * 64 + lane] + sV[j0 * 64 + lane] + b1);
    float h1b = frelu(sU[i1 * 64 + lane] + sV[j1 * 64 + lane] + b1);
    sH0[lane] = h1a;
    sH1[lane] = h1b;
    float h2a = frelu(dotR(sH0, w2, b2));
    float h2b = frelu(dotR(sH1, w2, b2));
    sH0[lane] = h2a;   // program-order after all h1 reads; same-wave LDS is in-order
    sH1[lane] = h2b;
    float e3a = dotR(sH0, w3, b3);
    float e3b = dotR(sH1, w3, b3);
    atomicAdd(&sAgg[i0 * 64 + lane], e3a);
    atomicAdd(&sAgg[j0 * 64 + lane], -e3a);
    atomicAdd(&sAgg[i1 * 64 + lane], e3b);
    atomicAdd(&sAgg[j1 * 64 + lane], -e3b);
  }
}

__global__ __launch_bounds__(THREADS, 1) void rld_kernel(Params P) {
  const int b = blockIdx.x;
  const int tid = (int)threadIdx.x;
  const int lane = tid & 63;
  const int wave = tid >> 6;
  const int cc = lane & 31;
  const int c16 = lane & 15;

  __shared__ float sU[NO * 64];
  __shared__ float sV[NO * 64];
  __shared__ float sAgg[NO * 64];
  __shared__ float sBig[NO * 256];   // A1: sSrc.  A3/B: sZC | sN | sM overlay.
  __shared__ float sH[8][2][64];
  __shared__ unsigned char sII[NPAIR];
  __shared__ unsigned char sJJ[NPAIR];
  float* sSrc = sBig;
  float* sZC = sBig;                 // [0, 2048)
  float* sN  = sBig + NO * 64;       // [2048, 4096)
  float* sM  = sBig + NO * 128;      // [4096, 6144)

  for (int p = tid; p < NPAIR; p += THREADS) {
    int i = 0, rem = p;
    while (rem >= 31 - i) { rem -= 31 - i; ++i; }
    sII[p] = (unsigned char)i;
    sJJ[p] = (unsigned char)(i + 1 + rem);
  }

  const float* zb = P.z + (size_t)b * NT * NO * NEE;
  float* sH0 = sH[wave][0];
  float* sH1 = sH[wave][1];
  const int i0r = wave, i1r = wave + 8, i2r = wave + 16, i3r = wave + 24;

  // ---- register-resident pair weights: ee columns for this lane ----
  float w2c[64], w3c[64];
#pragma unroll
  for (int k = 0; k < 64; ++k) {
    w2c[k] = P.ee2w[k * 64 + lane];
    w3c[k] = P.ee3w[k * 64 + lane];
  }

  // ===== Phase A1: u = src@ee1[:512], v = src@ee1[512:], s1 = src@ne1[:512] =====
  float au[4] = {0, 0, 0, 0}, av[4] = {0, 0, 0, 0}, s1r[4] = {0, 0, 0, 0};
  for (int half = 0; half < 2; ++half) {
    __syncthreads();
    for (int idx = tid; idx < NO * 256; idx += THREADS) {
      int i = idx >> 8, kk = idx & 255;
      int k = half * 256 + kk;
      int t = k >> 5, e = k & 31;
      float v = zb[(t * NO + i) * NEE + e];
      if (t > 0) v -= zb[((t - 1) * NO + i) * NEE + e];
      sSrc[i * 256 + kk] = v;
    }
    __syncthreads();
    const float* wA = P.ee1w + (half * 256) * 64 + lane;
    const float* wB = P.ee1w + (512 + half * 256) * 64 + lane;
    const float* wC = P.ne1w + (half * 256) * 64 + lane;
#pragma unroll 4
    for (int kk = 0; kk < 256; ++kk) {
      float wa = wA[kk * 64];
      float wb = wB[kk * 64];
      float wc = wC[kk * 64];
#pragma unroll
      for (int r = 0; r < 4; ++r) {
        float s = sSrc[(wave + 8 * r) * 256 + kk];
        au[r]  = fmaf(s, wa, au[r]);
        av[r]  = fmaf(s, wb, av[r]);
        s1r[r] = fmaf(s, wc, s1r[r]);
      }
    }
  }
  __syncthreads();  // all sSrc reads done before sU/sV writes & later overlay use
#pragma unroll
  for (int r = 0; r < 4; ++r) {
    sU[(wave + 8 * r) * 64 + lane] = au[r];
    sV[(wave + 8 * r) * 64 + lane] = av[r];
  }
  for (int idx = tid; idx < NO * 64; idx += THREADS) sAgg[idx] = 0.f;
  __syncthreads();

  // ===== Phase A2: ee edge MLP over 496 pairs (register weights) =====
  pair_block(sII, sJJ, sU, sV, sAgg, sH0, sH1, wave, lane,
             w2c, w3c, P.ee1b[lane], P.ee2b[lane], P.ee3b[lane]);

  // swap in le pair weights while waiting (private registers, no hazard)
#pragma unroll
  for (int k = 0; k < 64; ++k) {
    w2c[k] = P.le2w[k * 64 + lane];
    w3c[k] = P.le3w[k * 64 + lane];
  }
  __syncthreads();

  // ===== Phase A3: ne node MLP -> z_cur rows in sZC =====
  {
    float nb1 = P.ne1b[lane];
    float nb2 = P.ne2b[lane];
    float nb3 = P.ne3b[cc];
    float nb4 = P.ne4b[cc];
    float o1[4] = {s1r[0] + nb1, s1r[1] + nb1, s1r[2] + nb1, s1r[3] + nb1};
    dense4<16>(sAgg + i0r * 64, sAgg + i1r * 64, sAgg + i2r * 64, sAgg + i3r * 64,
               P.ne1w + 512 * 64 + lane, 64, o1);
    sN[i0r * 64 + lane] = frelu(o1[0]);
    sN[i1r * 64 + lane] = frelu(o1[1]);
    sN[i2r * 64 + lane] = frelu(o1[2]);
    sN[i3r * 64 + lane] = frelu(o1[3]);
    float o2[4] = {nb2, nb2, nb2, nb2};
    dense4<16>(sN + i0r * 64, sN + i1r * 64, sN + i2r * 64, sN + i3r * 64,
               P.ne2w + lane, 64, o2);
    sM[i0r * 64 + lane] = frelu(o2[0]);
    sM[i1r * 64 + lane] = frelu(o2[1]);
    sM[i2r * 64 + lane] = frelu(o2[2]);
    sM[i3r * 64 + lane] = frelu(o2[3]);
    float o3[4] = {nb3, nb3, nb3, nb3};
    dense4<16>(sM + i0r * 64, sM + i1r * 64, sM + i2r * 64, sM + i3r * 64,
               P.ne3w + cc, 32, o3);
    sN[i0r * 64 + cc] = frelu(o3[0]);   // both half-waves write identical values
    sN[i1r * 64 + cc] = frelu(o3[1]);
    sN[i2r * 64 + cc] = frelu(o3[2]);
    sN[i3r * 64 + cc] = frelu(o3[3]);
    float o4[4] = {nb4, nb4, nb4, nb4};
    dense4<8>(sN + i0r * 64, sN + i1r * 64, sN + i2r * 64, sN + i3r * 64,
              P.ne4w + cc, 32, o4);
    if (lane < 32) {
      sZC[i0r * 64 + lane] = zb[(15 * NO + i0r) * NEE + lane];
      sZC[i1r * 64 + lane] = zb[(15 * NO + i1r) * NEE + lane];
      sZC[i2r * 64 + lane] = zb[(15 * NO + i2r) * NEE + lane];
      sZC[i3r * 64 + lane] = zb[(15 * NO + i3r) * NEE + lane];
      sZC[i0r * 64 + 32 + lane] = o4[0];
      sZC[i1r * 64 + 32 + lane] = o4[1];
      sZC[i2r * 64 + 32 + lane] = o4[2];
      sZC[i3r * 64 + 32 + lane] = o4[3];
    }
  }

  float gb1 = P.le1b[lane];
  float gb2 = P.le2b[lane];
  float gb3 = P.le3b[lane];
  float lb1 = P.lt1b[lane];
  float lb2 = P.lt2b[lane];
  float lb3 = P.lt3b[cc];
  float lb4 = P.lt4b[c16];
  float lb5 = P.lt5b[lane];
  float* outb = P.out + (size_t)b * P.tf * NO * NEE;

  // ===== Phase B: t_future latent steps (2 barriers per step) =====
  for (int t = 0; t < P.tf; ++t) {
    {  // u/v from zc (le1), 4-row fused; zero agg (own rows)
      float ou[4] = {0, 0, 0, 0}, ov[4] = {0, 0, 0, 0};
      dense4<16>(sZC + i0r * 64, sZC + i1r * 64, sZC + i2r * 64, sZC + i3r * 64,
                 P.le1w + lane, 64, ou);
      dense4<16>(sZC + i0r * 64, sZC + i1r * 64, sZC + i2r * 64, sZC + i3r * 64,
                 P.le1w + 64 * 64 + lane, 64, ov);
#pragma unroll
      for (int r = 0; r < 4; ++r) {
        int i = wave + 8 * r;
        sU[i * 64 + lane] = ou[r];
        sV[i * 64 + lane] = ov[r];
        sAgg[i * 64 + lane] = 0.f;
      }
    }
    __syncthreads();
    pair_block(sII, sJJ, sU, sV, sAgg, sH0, sH1, wave, lane, w2c, w3c, gb1, gb2, gb3);
    __syncthreads();
    {  // lt node MLP, state update, output (own rows)
      float o1[4] = {lb1, lb1, lb1, lb1};
      dense4<16>(sZC + i0r * 64, sZC + i1r * 64, sZC + i2r * 64, sZC + i3r * 64,
                 P.lt1w + lane, 64, o1);
      dense4<16>(sAgg + i0r * 64, sAgg + i1r * 64, sAgg + i2r * 64, sAgg + i3r * 64,
                 P.lt1w + 64 * 64 + lane, 64, o1);
      sN[i0r * 64 + lane] = frelu(o1[0]);
      sN[i1r * 64 + lane] = frelu(o1[1]);
      sN[i2r * 64 + lane] = frelu(o1[2]);
      sN[i3r * 64 + lane] = frelu(o1[3]);
      float o2[4] = {lb2, lb2, lb2, lb2};
      dense4<16>(sN + i0r * 64, sN + i1r * 64, sN + i2r * 64, sN + i3r * 64,
                 P.lt2w + lane, 64, o2);
      sM[i0r * 64 + lane] = frelu(o2[0]);
      sM[i1r * 64 + lane] = frelu(o2[1]);
      sM[i2r * 64 + lane] = frelu(o2[2]);
      sM[i3r * 64 + lane] = frelu(o2[3]);
      float o3[4] = {lb3, lb3, lb3, lb3};
      dense4<16>(sM + i0r * 64, sM + i1r * 64, sM + i2r * 64, sM + i3r * 64,
                 P.lt3w + cc, 32, o3);
      sN[i0r * 64 + cc] = frelu(o3[0]);
      sN[i1r * 64 + cc] = frelu(o3[1]);
      sN[i2r * 64 + cc] = frelu(o3[2]);
      sN[i3r * 64 + cc] = frelu(o3[3]);
      float o4[4] = {lb4, lb4, lb4, lb4};
      dense4<8>(sN + i0r * 64, sN + i1r * 64, sN + i2r * 64, sN + i3r * 64,
                P.lt4w + c16, 16, o4);
      if (lane < 16) {
        sM[i0r * 64 + lane] = frelu(o4[0]);
        sM[i1r * 64 + lane] = frelu(o4[1]);
        sM[i2r * 64 + lane] = frelu(o4[2]);
        sM[i3r * 64 + lane] = frelu(o4[3]);
      }
      float o5[4] = {lb5, lb5, lb5, lb5};
      dense4<4>(sM + i0r * 64, sM + i1r * 64, sM + i2r * 64, sM + i3r * 64,
                P.lt5w + lane, 64, o5);
#pragma unroll
      for (int r = 0; r < 4; ++r) {
        int i = wave + 8 * r;
        float zn = sZC[i * 64 + lane] + o5[r];
        sZC[i * 64 + lane] = zn;
        if (lane < 32) outb[(t * NO + i) * NEE + lane] = zn;
      }
    }
  }
}

extern "C" void kernel_launch(void* const* d_in, const int* in_sizes, int n_in,
                              void* d_out, int out_size, void* d_ws, size_t ws_size,
                              hipStream_t stream) {
  (void)in_sizes; (void)n_in; (void)d_ws; (void)ws_size;
  Params P;
  int q = 0;
  P.z    = (fp)d_in[q++];
  P.ee1w = (fp)d_in[q++]; P.ee1b = (fp)d_in[q++];
  P.ee2w = (fp)d_in[q++]; P.ee2b = (fp)d_in[q++];
  P.ee3w = (fp)d_in[q++]; P.ee3b = (fp)d_in[q++];
  P.ne1w = (fp)d_in[q++]; P.ne1b = (fp)d_in[q++];
  P.ne2w = (fp)d_in[q++]; P.ne2b = (fp)d_in[q++];
  P.ne3w = (fp)d_in[q++]; P.ne3b = (fp)d_in[q++];
  P.ne4w = (fp)d_in[q++]; P.ne4b = (fp)d_in[q++];
  P.le1w = (fp)d_in[q++]; P.le1b = (fp)d_in[q++];
  P.le2w = (fp)d_in[q++]; P.le2b = (fp)d_in[q++];
  P.le3w = (fp)d_in[q++]; P.le3b = (fp)d_in[q++];
  P.lt1w = (fp)d_in[q++]; P.lt1b = (fp)d_in[q++];
  P.lt2w = (fp)d_in[q++]; P.lt2b = (fp)d_in[q++];
  P.lt3w = (fp)d_in[q++]; P.lt3b = (fp)d_in[q++];
  P.lt4w = (fp)d_in[q++]; P.lt4b = (fp)d_in[q++];
  P.lt5w = (fp)d_in[q++]; P.lt5b = (fp)d_in[q++];
  P.out = (float*)d_out;
  P.tf = out_size / (NB * NO * NEE);
  if (P.tf < 1) P.tf = 1;
  hipLaunchKernelGGL(rld_kernel, dim3(NB), dim3(THREADS), 0, stream, P);
}

// Round 6
// 2662.349 us; speedup vs baseline: 1.8972x; 1.0254x over previous
//
#include <hip/hip_runtime.h>

#define NB 256
#define NO 32
#define NEE 32
#define NT 16
#define NPAIR 496
#define THREADS 512

typedef const float* fp;

struct Params {
  fp z;
  fp ee1w, ee1b, ee2w, ee2b, ee3w, ee3b;
  fp ne1w, ne1b, ne2w, ne2b, ne3w, ne3b, ne4w, ne4b;
  fp le1w, le1b, le2w, le2b, le3w, le3b;
  fp lt1w, lt1b, lt2w, lt2b, lt3w, lt3b, lt4w, lt4b, lt5w, lt5b;
  float* out;
  int tf;
};

__device__ __forceinline__ float frelu(float x) { return x > 0.f ? x : 0.f; }

// 4-row fused dense layer (node MLPs): o[r] += sum_k x_r[k] * W[k*ldw].
// W pre-offset to this lane's output column; x_r are LDS rows read as uniform
// float4 (LDS broadcast); one weight load serves 4 rows.
template<int KC>
__device__ __forceinline__ void dense4(const float* x0, const float* x1,
                                       const float* x2, const float* x3,
                                       const float* W, int ldw, float o[4]) {
#pragma unroll
  for (int kc = 0; kc < KC; ++kc) {
    float w0 = W[(4 * kc + 0) * ldw];
    float w1 = W[(4 * kc + 1) * ldw];
    float w2 = W[(4 * kc + 2) * ldw];
    float w3 = W[(4 * kc + 3) * ldw];
    float4 a = *(const float4*)(x0 + 4 * kc);
    float4 b = *(const float4*)(x1 + 4 * kc);
    float4 c = *(const float4*)(x2 + 4 * kc);
    float4 d = *(const float4*)(x3 + 4 * kc);
    o[0] = fmaf(a.x, w0, o[0]); o[0] = fmaf(a.y, w1, o[0]); o[0] = fmaf(a.z, w2, o[0]); o[0] = fmaf(a.w, w3, o[0]);
    o[1] = fmaf(b.x, w0, o[1]); o[1] = fmaf(b.y, w1, o[1]); o[1] = fmaf(b.z, w2, o[1]); o[1] = fmaf(b.w, w3, o[1]);
    o[2] = fmaf(c.x, w0, o[2]); o[2] = fmaf(c.y, w1, o[2]); o[2] = fmaf(c.z, w2, o[2]); o[2] = fmaf(c.w, w3, o[2]);
    o[3] = fmaf(d.x, w0, o[3]); o[3] = fmaf(d.y, w1, o[3]); o[3] = fmaf(d.z, w2, o[3]); o[3] = fmaf(d.w, w3, o[3]);
  }
}

// Edge-MLP phase over this wave's 62 pairs, 2 pairs in flight, weights in
// float4 register arrays (constant indices only; expanded inline by macro so
// SROA keeps them in VGPRs).
#define PAIR_PHASE(B1, B2, B3)                                                  \
  do {                                                                          \
    const int base_ = wave * 62;                                                \
    for (int r_ = 0; r_ < 31; ++r_) {                                           \
      int p0_ = base_ + r_, p1_ = base_ + 31 + r_;                              \
      int i0_ = sII[p0_], j0_ = sJJ[p0_];                                       \
      int i1_ = sII[p1_], j1_ = sJJ[p1_];                                       \
      float h1a_ = frelu(sU[i0_ * 64 + lane] + sV[j0_ * 64 + lane] + (B1));     \
      float h1b_ = frelu(sU[i1_ * 64 + lane] + sV[j1_ * 64 + lane] + (B1));     \
      sH0[lane] = h1a_;                                                         \
      sH1[lane] = h1b_;                                                         \
      float pa0_ = (B2), pa1_ = 0.f, pa2_ = 0.f, pa3_ = 0.f;                    \
      float pb0_ = (B2), pb1_ = 0.f, pb2_ = 0.f, pb3_ = 0.f;                    \
      _Pragma("unroll")                                                         \
      for (int kc = 0; kc < 16; ++kc) {                                         \
        float4 w = w2v[kc];                                                     \
        float4 xa = *(const float4*)(sH0 + 4 * kc);                             \
        float4 xb = *(const float4*)(sH1 + 4 * kc);                             \
        pa0_ = fmaf(xa.x, w.x, pa0_); pa1_ = fmaf(xa.y, w.y, pa1_);             \
        pa2_ = fmaf(xa.z, w.z, pa2_); pa3_ = fmaf(xa.w, w.w, pa3_);             \
        pb0_ = fmaf(xb.x, w.x, pb0_); pb1_ = fmaf(xb.y, w.y, pb1_);             \
        pb2_ = fmaf(xb.z, w.z, pb2_); pb3_ = fmaf(xb.w, w.w, pb3_);             \
      }                                                                         \
      float h2a_ = frelu((pa0_ + pa1_) + (pa2_ + pa3_));                        \
      float h2b_ = frelu((pb0_ + pb1_) + (pb2_ + pb3_));                        \
      sH0[lane] = h2a_;                                                         \
      sH1[lane] = h2b_;                                                         \
      float qa0_ = (B3), qa1_ = 0.f, qa2_ = 0.f, qa3_ = 0.f;                    \
      float qb0_ = (B3), qb1_ = 0.f, qb2_ = 0.f, qb3_ = 0.f;                    \
      _Pragma("unroll")                                                         \
      for (int kc = 0; kc < 16; ++kc) {                                         \
        float4 w = w3v[kc];                                                     \
        float4 xa = *(const float4*)(sH0 + 4 * kc);                             \
        float4 xb = *(const float4*)(sH1 + 4 * kc);                             \
        qa0_ = fmaf(xa.x, w.x, qa0_); qa1_ = fmaf(xa.y, w.y, qa1_);             \
        qa2_ = fmaf(xa.z, w.z, qa2_); qa3_ = fmaf(xa.w, w.w, qa3_);             \
        qb0_ = fmaf(xb.x, w.x, qb0_); qb1_ = fmaf(xb.y, w.y, qb1_);             \
        qb2_ = fmaf(xb.z, w.z, qb2_); qb3_ = fmaf(xb.w, w.w, qb3_);             \
      }                                                                         \
      float e3a_ = (qa0_ + qa1_) + (qa2_ + qa3_);                               \
      float e3b_ = (qb0_ + qb1_) + (qb2_ + qb3_);                               \
      atomicAdd(&sAgg[i0_ * 64 + lane], e3a_);                                  \
      atomicAdd(&sAgg[j0_ * 64 + lane], -e3a_);                                 \
      atomicAdd(&sAgg[i1_ * 64 + lane], e3b_);                                  \
      atomicAdd(&sAgg[j1_ * 64 + lane], -e3b_);                                 \
    }                                                                           \
  } while (0)

__global__ __launch_bounds__(THREADS, 2) void rld_kernel(Params P) {
  const int b = blockIdx.x;
  const int tid = (int)threadIdx.x;
  const int lane = tid & 63;
  const int wave = tid >> 6;
  const int cc = lane & 31;
  const int c16 = lane & 15;

  __shared__ float sU[NO * 64];
  __shared__ float sV[NO * 64];
  __shared__ float sAgg[NO * 64];
  __shared__ float sBig[NO * 256];   // A1: sSrc.  A3/B: sZC | sN | sM overlay.
  __shared__ float sH[8][2][64];
  __shared__ unsigned char sII[NPAIR];
  __shared__ unsigned char sJJ[NPAIR];
  float* sSrc = sBig;
  float* sZC = sBig;                 // [0, 2048)
  float* sN  = sBig + NO * 64;       // [2048, 4096)
  float* sM  = sBig + NO * 128;      // [4096, 6144)

  for (int p = tid; p < NPAIR; p += THREADS) {
    int i = 0, rem = p;
    while (rem >= 31 - i) { rem -= 31 - i; ++i; }
    sII[p] = (unsigned char)i;
    sJJ[p] = (unsigned char)(i + 1 + rem);
  }

  const float* zb = P.z + (size_t)b * NT * NO * NEE;
  float* sH0 = sH[wave][0];
  float* sH1 = sH[wave][1];
  const int i0r = wave, i1r = wave + 8, i2r = wave + 16, i3r = wave + 24;

  // ---- register-resident pair weights: this lane's ee2/ee3 columns ----
  float4 w2v[16], w3v[16];
#pragma unroll
  for (int kc = 0; kc < 16; ++kc) {
    w2v[kc].x = P.ee2w[(4 * kc + 0) * 64 + lane];
    w2v[kc].y = P.ee2w[(4 * kc + 1) * 64 + lane];
    w2v[kc].z = P.ee2w[(4 * kc + 2) * 64 + lane];
    w2v[kc].w = P.ee2w[(4 * kc + 3) * 64 + lane];
    w3v[kc].x = P.ee3w[(4 * kc + 0) * 64 + lane];
    w3v[kc].y = P.ee3w[(4 * kc + 1) * 64 + lane];
    w3v[kc].z = P.ee3w[(4 * kc + 2) * 64 + lane];
    w3v[kc].w = P.ee3w[(4 * kc + 3) * 64 + lane];
  }

  // ===== Phase A1: u = src@ee1[:512], v = src@ee1[512:], s1 = src@ne1[:512] =====
  float au[4] = {0, 0, 0, 0}, av[4] = {0, 0, 0, 0}, s1r[4] = {0, 0, 0, 0};
  for (int half = 0; half < 2; ++half) {
    __syncthreads();
    for (int idx = tid; idx < NO * 256; idx += THREADS) {
      int i = idx >> 8, kk = idx & 255;
      int k = half * 256 + kk;
      int t = k >> 5, e = k & 31;
      float v = zb[(t * NO + i) * NEE + e];
      if (t > 0) v -= zb[((t - 1) * NO + i) * NEE + e];
      sSrc[i * 256 + kk] = v;
    }
    __syncthreads();
    const float* wA = P.ee1w + (half * 256) * 64 + lane;
    const float* wB = P.ee1w + (512 + half * 256) * 64 + lane;
    const float* wC = P.ne1w + (half * 256) * 64 + lane;
#pragma unroll 4
    for (int kk = 0; kk < 256; ++kk) {
      float wa = wA[kk * 64];
      float wb = wB[kk * 64];
      float wc = wC[kk * 64];
#pragma unroll
      for (int r = 0; r < 4; ++r) {
        float s = sSrc[(wave + 8 * r) * 256 + kk];
        au[r]  = fmaf(s, wa, au[r]);
        av[r]  = fmaf(s, wb, av[r]);
        s1r[r] = fmaf(s, wc, s1r[r]);
      }
    }
  }
  __syncthreads();  // all sSrc reads done before sU/sV writes & overlay reuse
#pragma unroll
  for (int r = 0; r < 4; ++r) {
    sU[(wave + 8 * r) * 64 + lane] = au[r];
    sV[(wave + 8 * r) * 64 + lane] = av[r];
  }
  for (int idx = tid; idx < NO * 64; idx += THREADS) sAgg[idx] = 0.f;
  __syncthreads();

  // ===== Phase A2: ee edge MLP over 496 pairs =====
  {
    float eb1 = P.ee1b[lane], eb2 = P.ee2b[lane], eb3 = P.ee3b[lane];
    PAIR_PHASE(eb1, eb2, eb3);
  }

  // swap in le pair weights (private registers, no hazard with others' work)
#pragma unroll
  for (int kc = 0; kc < 16; ++kc) {
    w2v[kc].x = P.le2w[(4 * kc + 0) * 64 + lane];
    w2v[kc].y = P.le2w[(4 * kc + 1) * 64 + lane];
    w2v[kc].z = P.le2w[(4 * kc + 2) * 64 + lane];
    w2v[kc].w = P.le2w[(4 * kc + 3) * 64 + lane];
    w3v[kc].x = P.le3w[(4 * kc + 0) * 64 + lane];
    w3v[kc].y = P.le3w[(4 * kc + 1) * 64 + lane];
    w3v[kc].z = P.le3w[(4 * kc + 2) * 64 + lane];
    w3v[kc].w = P.le3w[(4 * kc + 3) * 64 + lane];
  }
  __syncthreads();

  // ===== Phase A3: ne node MLP -> z_cur rows in sZC =====
  {
    float nb1 = P.ne1b[lane];
    float nb2 = P.ne2b[lane];
    float nb3 = P.ne3b[cc];
    float nb4 = P.ne4b[cc];
    float o1[4] = {s1r[0] + nb1, s1r[1] + nb1, s1r[2] + nb1, s1r[3] + nb1};
    dense4<16>(sAgg + i0r * 64, sAgg + i1r * 64, sAgg + i2r * 64, sAgg + i3r * 64,
               P.ne1w + 512 * 64 + lane, 64, o1);
    sN[i0r * 64 + lane] = frelu(o1[0]);
    sN[i1r * 64 + lane] = frelu(o1[1]);
    sN[i2r * 64 + lane] = frelu(o1[2]);
    sN[i3r * 64 + lane] = frelu(o1[3]);
    float o2[4] = {nb2, nb2, nb2, nb2};
    dense4<16>(sN + i0r * 64, sN + i1r * 64, sN + i2r * 64, sN + i3r * 64,
               P.ne2w + lane, 64, o2);
    sM[i0r * 64 + lane] = frelu(o2[0]);
    sM[i1r * 64 + lane] = frelu(o2[1]);
    sM[i2r * 64 + lane] = frelu(o2[2]);
    sM[i3r * 64 + lane] = frelu(o2[3]);
    float o3[4] = {nb3, nb3, nb3, nb3};
    dense4<16>(sM + i0r * 64, sM + i1r * 64, sM + i2r * 64, sM + i3r * 64,
               P.ne3w + cc, 32, o3);
    sN[i0r * 64 + cc] = frelu(o3[0]);   // both half-waves write identical values
    sN[i1r * 64 + cc] = frelu(o3[1]);
    sN[i2r * 64 + cc] = frelu(o3[2]);
    sN[i3r * 64 + cc] = frelu(o3[3]);
    float o4[4] = {nb4, nb4, nb4, nb4};
    dense4<8>(sN + i0r * 64, sN + i1r * 64, sN + i2r * 64, sN + i3r * 64,
              P.ne4w + cc, 32, o4);
    if (lane < 32) {
      sZC[i0r * 64 + lane] = zb[(15 * NO + i0r) * NEE + lane];
      sZC[i1r * 64 + lane] = zb[(15 * NO + i1r) * NEE + lane];
      sZC[i2r * 64 + lane] = zb[(15 * NO + i2r) * NEE + lane];
      sZC[i3r * 64 + lane] = zb[(15 * NO + i3r) * NEE + lane];
      sZC[i0r * 64 + 32 + lane] = o4[0];
      sZC[i1r * 64 + 32 + lane] = o4[1];
      sZC[i2r * 64 + 32 + lane] = o4[2];
      sZC[i3r * 64 + 32 + lane] = o4[3];
    }
  }

  float gb1 = P.le1b[lane];
  float gb2 = P.le2b[lane];
  float gb3 = P.le3b[lane];
  float lb1 = P.lt1b[lane];
  float lb2 = P.lt2b[lane];
  float lb3 = P.lt3b[cc];
  float lb4 = P.lt4b[c16];
  float lb5 = P.lt5b[lane];
  float* outb = P.out + (size_t)b * P.tf * NO * NEE;

  // ===== Phase B: t_future latent steps (2 barriers per step) =====
  for (int t = 0; t < P.tf; ++t) {
    {  // u/v from zc (le1), 4-row fused; zero agg (own rows)
      float ou[4] = {0, 0, 0, 0}, ov[4] = {0, 0, 0, 0};
      dense4<16>(sZC + i0r * 64, sZC + i1r * 64, sZC + i2r * 64, sZC + i3r * 64,
                 P.le1w + lane, 64, ou);
      dense4<16>(sZC + i0r * 64, sZC + i1r * 64, sZC + i2r * 64, sZC + i3r * 64,
                 P.le1w + 64 * 64 + lane, 64, ov);
#pragma unroll
      for (int r = 0; r < 4; ++r) {
        int i = wave + 8 * r;
        sU[i * 64 + lane] = ou[r];
        sV[i * 64 + lane] = ov[r];
        sAgg[i * 64 + lane] = 0.f;
      }
    }
    __syncthreads();
    PAIR_PHASE(gb1, gb2, gb3);
    __syncthreads();
    {  // lt node MLP, state update, output (own rows)
      float o1[4] = {lb1, lb1, lb1, lb1};
      dense4<16>(sZC + i0r * 64, sZC + i1r * 64, sZC + i2r * 64, sZC + i3r * 64,
                 P.lt1w + lane, 64, o1);
      dense4<16>(sAgg + i0r * 64, sAgg + i1r * 64, sAgg + i2r * 64, sAgg + i3r * 64,
                 P.lt1w + 64 * 64 + lane, 64, o1);
      sN[i0r * 64 + lane] = frelu(o1[0]);
      sN[i1r * 64 + lane] = frelu(o1[1]);
      sN[i2r * 64 + lane] = frelu(o1[2]);
      sN[i3r * 64 + lane] = frelu(o1[3]);
      float o2[4] = {lb2, lb2, lb2, lb2};
      dense4<16>(sN + i0r * 64, sN + i1r * 64, sN + i2r * 64, sN + i3r * 64,
                 P.lt2w + lane, 64, o2);
      sM[i0r * 64 + lane] = frelu(o2[0]);
      sM[i1r * 64 + lane] = frelu(o2[1]);
      sM[i2r * 64 + lane] = frelu(o2[2]);
      sM[i3r * 64 + lane] = frelu(o2[3]);
      float o3[4] = {lb3, lb3, lb3, lb3};
      dense4<16>(sM + i0r * 64, sM + i1r * 64, sM + i2r * 64, sM + i3r * 64,
                 P.lt3w + cc, 32, o3);
      sN[i0r * 64 + cc] = frelu(o3[0]);
      sN[i1r * 64 + cc] = frelu(o3[1]);
      sN[i2r * 64 + cc] = frelu(o3[2]);
      sN[i3r * 64 + cc] = frelu(o3[3]);
      float o4[4] = {lb4, lb4, lb4, lb4};
      dense4<8>(sN + i0r * 64, sN + i1r * 64, sN + i2r * 64, sN + i3r * 64,
                P.lt4w + c16, 16, o4);
      if (lane < 16) {
        sM[i0r * 64 + lane] = frelu(o4[0]);
        sM[i1r * 64 + lane] = frelu(o4[1]);
        sM[i2r * 64 + lane] = frelu(o4[2]);
        sM[i3r * 64 + lane] = frelu(o4[3]);
      }
      float o5[4] = {lb5, lb5, lb5, lb5};
      dense4<4>(sM + i0r * 64, sM + i1r * 64, sM + i2r * 64, sM + i3r * 64,
                P.lt5w + lane, 64, o5);
#pragma unroll
      for (int r = 0; r < 4; ++r) {
        int i = wave + 8 * r;
        float zn = sZC[i * 64 + lane] + o5[r];
        sZC[i * 64 + lane] = zn;
        if (lane < 32) outb[(t * NO + i) * NEE + lane] = zn;
      }
    }
  }
}

extern "C" void kernel_launch(void* const* d_in, const int* in_sizes, int n_in,
                              void* d_out, int out_size, void* d_ws, size_t ws_size,
                              hipStream_t stream) {
  (void)in_sizes; (void)n_in; (void)d_ws; (void)ws_size;
  Params P;
  int q = 0;
  P.z    = (fp)d_in[q++];
  P.ee1w = (fp)d_in[q++]; P.ee1b = (fp)d_in[q++];
  P.ee2w = (fp)d_in[q++]; P.ee2b = (fp)d_in[q++];
  P.ee3w = (fp)d_in[q++]; P.ee3b = (fp)d_in[q++];
  P.ne1w = (fp)d_in[q++]; P.ne1b = (fp)d_in[q++];
  P.ne2w = (fp)d_in[q++]; P.ne2b = (fp)d_in[q++];
  P.ne3w = (fp)d_in[q++]; P.ne3b = (fp)d_in[q++];
  P.ne4w = (fp)d_in[q++]; P.ne4b = (fp)d_in[q++];
  P.le1w = (fp)d_in[q++]; P.le1b = (fp)d_in[q++];
  P.le2w = (fp)d_in[q++]; P.le2b = (fp)d_in[q++];
  P.le3w = (fp)d_in[q++]; P.le3b = (fp)d_in[q++];
  P.lt1w = (fp)d_in[q++]; P.lt1b = (fp)d_in[q++];
  P.lt2w = (fp)d_in[q++]; P.lt2b = (fp)d_in[q++];
  P.lt3w = (fp)d_in[q++]; P.lt3b = (fp)d_in[q++];
  P.lt4w = (fp)d_in[q++]; P.lt4b = (fp)d_in[q++];
  P.lt5w = (fp)d_in[q++]; P.lt5b = (fp)d_in[q++];
  P.out = (float*)d_out;
  P.tf = out_size / (NB * NO * NEE);
  if (P.tf < 1) P.tf = 1;
  hipLaunchKernelGGL(rld_kernel, dim3(NB), dim3(THREADS), 0, stream, P);
}